// Round 22
// baseline (140.818 us; speedup 1.0000x reference)
//
#include <hip/hip_runtime.h>

typedef __bf16 bf16x8 __attribute__((ext_vector_type(8)));
typedef float f32x4 __attribute__((ext_vector_type(4)));

#define N_TOK 8192
#define DMODEL 1024
#define NEXP 64
#define ESIZE 128
#define WL_MAX 576    // sum ceil(ck/64) <= 32768/64 + 64 = 576 (divisible by 8)
#define PREP_SPLIT 2064  // 2048 blocks for x + 16 for esel (16 elems/thread)

__device__ __forceinline__ unsigned short f2bf(float f) {
  unsigned int u = __builtin_bit_cast(unsigned int, f);
  u += 0x7FFFu + ((u >> 16) & 1u);
  return (unsigned short)(u >> 16);
}

__device__ __forceinline__ float b2f(unsigned short u) {
  unsigned int v = ((unsigned int)u) << 16;
  return __builtin_bit_cast(float, v);
}

// async global->LDS, 16B per lane. LDS dest lane-linear within the wave.
__device__ __forceinline__ void gld16(unsigned short* lds, const unsigned short* g) {
  __builtin_amdgcn_global_load_lds(
      (const __attribute__((address_space(1))) unsigned int*)g,
      (__attribute__((address_space(3))) unsigned int*)lds, 16, 0, 0);
}

// K1: split-only prep — fp32->bf16 hi/lo split of x and expert_sel
// (16 elems/thread) + zero cnt. Transpose lives in k_rlogit's grid.
__global__ void k_prep(const float* __restrict__ x, unsigned short* __restrict__ xh,
                       unsigned short* __restrict__ xl, const float* __restrict__ esel,
                       unsigned short* __restrict__ sh_, unsigned short* __restrict__ sl_,
                       int* __restrict__ zeroPtr) {
  int bid = blockIdx.x, tid = threadIdx.x;
  if (bid == 0 && tid < 128) zeroPtr[tid] = 0;
  size_t gid = (size_t)bid * 256 + tid;
  const size_t NX = (size_t)N_TOK * DMODEL / 16;
  const float* in;
  unsigned short *ho, *lo2;
  size_t i;
  if (gid < NX) {
    in = x; ho = xh; lo2 = xl; i = gid * 16;
  } else {
    in = esel; ho = sh_; lo2 = sl_; i = (gid - NX) * 16;
  }
#pragma unroll
  for (int c = 0; c < 2; ++c) {
    size_t ii = i + c * 8;
    float4 a = *reinterpret_cast<const float4*>(in + ii);
    float4 b = *reinterpret_cast<const float4*>(in + ii + 4);
    unsigned short h[8], l[8];
    float v[8] = {a.x, a.y, a.z, a.w, b.x, b.y, b.z, b.w};
#pragma unroll
    for (int q = 0; q < 8; ++q) {
      h[q] = f2bf(v[q]);
      l[q] = f2bf(v[q] - b2f(h[q]));
    }
    uint4 oh, ol;
    oh.x = h[0] | ((unsigned)h[1] << 16); oh.y = h[2] | ((unsigned)h[3] << 16);
    oh.z = h[4] | ((unsigned)h[5] << 16); oh.w = h[6] | ((unsigned)h[7] << 16);
    ol.x = l[0] | ((unsigned)l[1] << 16); ol.y = l[2] | ((unsigned)l[3] << 16);
    ol.z = l[4] | ((unsigned)l[5] << 16); ol.w = l[6] | ((unsigned)l[7] << 16);
    *reinterpret_cast<uint4*>(ho + ii) = oh;
    *reinterpret_cast<uint4*>(lo2 + ii) = ol;
  }
}

// K3: router + overlapped keys/values transpose (r21-validated structure).
// Blocks [0,256): bf16x3 MFMA logit GEMM; logits overlay stage after the loop.
// Blocks [256, 2304): 64x64 transpose+cast tiles (2 per block).
// Epilogue writes per-token near-tie flags (deterministic) for in-bucket refine.
__global__ __launch_bounds__(512) void k_rlogit(const unsigned short* __restrict__ xh,
                                                const unsigned short* __restrict__ xl,
                                                const unsigned short* __restrict__ sh,
                                                const unsigned short* __restrict__ sl,
                                                const float* __restrict__ keys,
                                                unsigned short* __restrict__ kout,
                                                const float* __restrict__ values,
                                                unsigned short* __restrict__ vout,
                                                int4* __restrict__ idx4,
                                                float4* __restrict__ g4,
                                                int* __restrict__ flags) {
  int tid = threadIdx.x, lane = tid & 63;

  __shared__ alignas(16) unsigned short stage[24576];  // 48KB (union: dbuf / tiles / logits)

  if (blockIdx.x >= 256) {
    // ---- transpose path: 2 independent 64x64 tiles per block
    int tt = (blockIdx.x - 256) * 2 + (tid >> 8);  // 0..4095
    int ts = tid & 255;
    float* tb = (float*)stage + (tid >> 8) * (64 * 65);  // 2 x 16.6KB <= 48KB
    const float* in;
    unsigned short* out;
    int R, C;
    if (tt < 2048) { in = keys; out = kout; R = DMODEL; C = ESIZE; }
    else { in = values; out = vout; R = ESIZE; C = DMODEL; tt -= 2048; }
    int b = tt >> 5, tile = tt & 31;
    int tilesC = C >> 6;
    int tr = tile / tilesC, tc = tile % tilesC;
    const float* ip = in + (size_t)b * R * C + (size_t)tr * 64 * C + tc * 64;
    unsigned short* op = out + (size_t)b * R * C + (size_t)tc * 64 * R + tr * 64;

    int lr = ts >> 4, lc4 = (ts & 15) * 4;
#pragma unroll
    for (int p = 0; p < 4; ++p) {
      int row = p * 16 + lr;
      *reinterpret_cast<float4*>(&tb[row * 65 + lc4]) =
          *reinterpret_cast<const float4*>(ip + (size_t)row * C + lc4);
    }
    __syncthreads();
    int orow = ts >> 3, oc = (ts & 7) * 8;
#pragma unroll
    for (int p = 0; p < 2; ++p) {
      int row = p * 32 + orow;
      unsigned short h[8];
#pragma unroll
      for (int j = 0; j < 8; ++j) h[j] = f2bf(tb[(oc + j) * 65 + row]);
      uint4 ov;
      ov.x = h[0] | ((unsigned)h[1] << 16); ov.y = h[2] | ((unsigned)h[3] << 16);
      ov.z = h[4] | ((unsigned)h[5] << 16); ov.w = h[6] | ((unsigned)h[7] << 16);
      *reinterpret_cast<uint4*>(op + (size_t)row * R + oc) = ov;
    }
    return;
  }

  // ---- routing path
  int tok0 = blockIdx.x * 32;
  int wv = tid >> 6, wr = wv >> 2, wc = wv & 3;
  int cc = lane & 15, grp = lane >> 4;

  int aslot = tid & 255;
  int arow = aslot >> 3, ach = aslot & 7;
  const unsigned short* srcA = (tid < 256 ? xh : xl) +
      (size_t)(tok0 + arow) * DMODEL + ((ach ^ (arow & 7)) * 8);
  int brow = tid >> 3, bch = tid & 7;  // 64 rows x 8 chunks
  int bsw = (bch ^ (brow & 7)) * 8;
  const unsigned short* srcBh = sh + (size_t)brow * DMODEL + bsw;
  const unsigned short* srcBl = sl + (size_t)brow * DMODEL + bsw;

  auto stg = [&](int bo /*ushort offset*/, int kk) {
    unsigned short* s = stage + bo;
    gld16(s + tid * 8, srcA + kk);          // Ah ushorts [0,2048) | Al [2048,4096)
    gld16(s + 4096 + tid * 8, srcBh + kk);  // Bh ushorts [4096,8192)
    gld16(s + 8192 + tid * 8, srcBl + kk);  // Bl ushorts [8192,12288)
  };

  f32x4 acc = {};
  stg(0, 0);
  __syncthreads();
  const char* sb = (const char*)stage;
  int ra = wr * 16 + cc;
  int rb = wc * 16 + cc;
  for (int t = 0; t < 16; ++t) {
    int curB = (t & 1) * 24576;  // bytes
    if (t < 15) stg(((t + 1) & 1) * 12288, (t + 1) * 64);
#pragma unroll
    for (int ks = 0; ks < 2; ++ks) {
      int o_a = (((ks * 4 + grp) ^ (ra & 7)) * 16);
      int o_b = (((ks * 4 + grp) ^ (rb & 7)) * 16);
      bf16x8 aH = *reinterpret_cast<const bf16x8*>(sb + curB + ra * 128 + o_a);
      bf16x8 aL = *reinterpret_cast<const bf16x8*>(sb + curB + 4096 + ra * 128 + o_a);
      bf16x8 bH = *reinterpret_cast<const bf16x8*>(sb + curB + 8192 + rb * 128 + o_b);
      bf16x8 bL = *reinterpret_cast<const bf16x8*>(sb + curB + 16384 + rb * 128 + o_b);
      acc = __builtin_amdgcn_mfma_f32_16x16x32_bf16(aH, bH, acc, 0, 0, 0);
      acc = __builtin_amdgcn_mfma_f32_16x16x32_bf16(aH, bL, acc, 0, 0, 0);
      acc = __builtin_amdgcn_mfma_f32_16x16x32_bf16(aL, bH, acc, 0, 0, 0);
    }
    __syncthreads();
  }
  // Final barrier retired ALL stage reads -> overlay logits at stage bytes [0,8704).

  float* lg = (float*)stage;  // [32][68] overlay
  // C layout (verified): col(expert) = lane&15, row(token) = grp*4 + r
#pragma unroll
  for (int r = 0; r < 4; ++r)
    lg[(wr * 16 + grp * 4 + r) * 68 + wc * 16 + cc] = acc[r];
  __syncthreads();

  if (tid < 32) {
    float bv0 = -3e38f, bv1 = -3e38f, bv2 = -3e38f, bv3 = -3e38f, bv4 = -3e38f;
    int bi0 = 0, bi1 = 0, bi2 = 0, bi3 = 0;
    for (int e = 0; e < 64; ++e) {
      float v = lg[tid * 68 + e];
      if (v > bv4) {
        if (v > bv0) {
          bv4 = bv3; bv3 = bv2; bi3 = bi2; bv2 = bv1; bi2 = bi1; bv1 = bv0; bi1 = bi0; bv0 = v; bi0 = e;
        } else if (v > bv1) {
          bv4 = bv3; bv3 = bv2; bi3 = bi2; bv2 = bv1; bi2 = bi1; bv1 = v; bi1 = e;
        } else if (v > bv2) {
          bv4 = bv3; bv3 = bv2; bi3 = bi2; bv2 = v; bi2 = e;
        } else if (v > bv3) {
          bv4 = bv3; bv3 = v; bi3 = e;
        } else {
          bv4 = v;
        }
      }
    }
    idx4[tok0 + tid] = make_int4(bi0, bi1, bi2, bi3);
    float4 g;
    g.x = 1.0f / (1.0f + __expf(-bv0));
    g.y = 1.0f / (1.0f + __expf(-bv1));
    g.z = 1.0f / (1.0f + __expf(-bv2));
    g.w = 1.0f / (1.0f + __expf(-bv3));
    g4[tok0 + tid] = g;
    flags[tok0 + tid] = (bv3 - bv4 < 1e-4f) ? 1 : 0;
  }
}

// K4: bucketize + in-block exact fp64 refine of flagged near-tie tokens.
// Each block refines ONLY its own 256 tokens' flags (expected 0-2), then buckets.
__global__ __launch_bounds__(256) void k_bucket(int4* __restrict__ idx4,
                                                float4* __restrict__ g4,
                                                const float* __restrict__ x,
                                                const float* __restrict__ esel,
                                                const int* __restrict__ flags,
                                                int* __restrict__ btok,
                                                float* __restrict__ bgate,
                                                int* __restrict__ cnt) {
  __shared__ int lcnt[64];
  __shared__ int lbase[64];
  __shared__ int flist[256];
  __shared__ int fnum;
  __shared__ double lp[256];
  __shared__ double lgt[64];
  int tid = threadIdx.x;
  int n = blockIdx.x * 256 + tid;
  if (tid == 0) fnum = 0;
  if (tid < 64) lcnt[tid] = 0;
  __syncthreads();
  if (flags[n]) {
    int p = atomicAdd(&fnum, 1);
    flist[p] = n;
  }
  __syncthreads();
  int nf = fnum;
  for (int f = 0; f < nf; ++f) {
    int nn = flist[f];
    int e = tid & 63, jq = tid >> 6;
    const float* xr = x + (size_t)nn * DMODEL + jq * 256;
    const float* er = esel + (size_t)e * DMODEL + jq * 256;
    double s = 0.0;
    for (int j = 0; j < 256; ++j)
      s += (double)xr[j] * (double)er[j];
    lp[tid] = s;
    __syncthreads();
    if (tid < 64)
      lgt[tid] = lp[tid] + lp[64 + tid] + lp[128 + tid] + lp[192 + tid];
    __syncthreads();
    if (tid == 0) {
      double bv0 = -1.0e300, bv1 = -1.0e300, bv2 = -1.0e300, bv3 = -1.0e300;
      int bi0 = 0, bi1 = 0, bi2 = 0, bi3 = 0;
      for (int e2 = 0; e2 < 64; ++e2) {
        double v = lgt[e2];
        if (v > bv3) {
          if (v > bv0) {
            bv3 = bv2; bi3 = bi2; bv2 = bv1; bi2 = bi1; bv1 = bv0; bi1 = bi0; bv0 = v; bi0 = e2;
          } else if (v > bv1) {
            bv3 = bv2; bi3 = bi2; bv2 = bv1; bi2 = bi1; bv1 = v; bi1 = e2;
          } else if (v > bv2) {
            bv3 = bv2; bi3 = bi2; bv2 = v; bi2 = e2;
          } else {
            bv3 = v; bi3 = e2;
          }
        }
      }
      idx4[nn] = make_int4(bi0, bi1, bi2, bi3);
      float4 g;
      g.x = 1.0f / (1.0f + __expf(-(float)bv0));
      g.y = 1.0f / (1.0f + __expf(-(float)bv1));
      g.z = 1.0f / (1.0f + __expf(-(float)bv2));
      g.w = 1.0f / (1.0f + __expf(-(float)bv3));
      g4[nn] = g;
    }
    __syncthreads();
  }

  // ---- bucketize (refined idx4/g4 visible: same-block writes + barriers above)
  int4 I = idx4[n];
  float4 G = g4[n];
  int e[4] = {I.x, I.y, I.z, I.w};
  float g[4] = {G.x, G.y, G.z, G.w};
  int pos[4];
#pragma unroll
  for (int h = 0; h < 4; ++h) pos[h] = atomicAdd(&lcnt[e[h]], 1);
  __syncthreads();
  if (tid < 64 && lcnt[tid] > 0) lbase[tid] = atomicAdd(&cnt[tid], lcnt[tid]);
  __syncthreads();
#pragma unroll
  for (int h = 0; h < 4; ++h) {
    int slot = lbase[e[h]] + pos[h];
    btok[e[h] * N_TOK + slot] = h * N_TOK + n;
    bgate[e[h] * N_TOK + slot] = g[h];
  }
}

// K6: fused per-(expert,tile64), r11 barrier structure, LDS OVERLAY, and
// inlined worklist: each block derives (k, tile) from cnt via 64-lane scan.
__global__ __launch_bounds__(512, 6) void k_expert(
    const unsigned short* __restrict__ xbf, const unsigned short* __restrict__ kbf,
    const unsigned short* __restrict__ vbf, const int* __restrict__ btok,
    const float* __restrict__ bgate, const int* __restrict__ cnt,
    unsigned short* __restrict__ part) {
  int wid = (blockIdx.x & 7) * (WL_MAX / 8) + (blockIdx.x >> 3);
  int tid = threadIdx.x, lane = tid & 63;

  __shared__ alignas(16) unsigned short stage[25088];  // 50176 B, multi-purpose
  __shared__ int sRow[64];
  __shared__ float sGate[64];
  __shared__ int s_kt;

  // ---- inlined worklist: (k, tile) from cnt prefix-scan (wave 0)
  if (tid == 0) s_kt = -1;
  if (tid < 64) {
    int nt_ = (cnt[tid] + 63) >> 6;
    int off = nt_;
#pragma unroll
    for (int d = 1; d < 64; d <<= 1) {
      int o = __shfl_up(off, d);
      if (lane >= d) off += o;
    }
    int lo = off - nt_;
    if (wid >= lo && wid < off) s_kt = (tid << 8) | (wid - lo);
  }
  __syncthreads();
  int kt = s_kt;
  if (kt < 0) return;
  int k = kt >> 8, tile = kt & 255;
  int ck = cnt[k];

  int wv = tid >> 6, wr = wv >> 2, wc = wv & 3;
  int cc = lane & 15, grp = lane >> 4;

  if (tid < 64) {
    int i = tile * 64 + tid;
    bool valid = i < ck;
    sRow[tid] = valid ? btok[k * N_TOK + i] : 4 * N_TOK + wid;  // per-block dump row
    sGate[tid] = valid ? bgate[k * N_TOK + i] : 0.0f;
  }
  __syncthreads();

  const unsigned short* kb = kbf + (size_t)k * (ESIZE * DMODEL);
  const unsigned short* vb = vbf + (size_t)k * (DMODEL * ESIZE);
  char* sbase = (char*)stage;

  // ---- GEMM1 staging bases (src chunk = phys ^ (row&7), LDS dest lane-linear)
  int arow = tid >> 3, ach = tid & 7;
  const unsigned short* srcA =
      xbf + (size_t)(sRow[arow] & (N_TOK - 1)) * DMODEL + ((ach ^ (arow & 7)) * 8);
  int b1row = 64 + arow;
  const unsigned short* srcB0 = kb + (size_t)arow * DMODEL + ((ach ^ (arow & 7)) * 8);
  const unsigned short* srcB1 = kb + (size_t)b1row * DMODEL + ((ach ^ (b1row & 7)) * 8);

  auto stg1 = [&](int boB, int kk) {
    unsigned short* s = (unsigned short*)(sbase + boB);
    gld16(s + tid * 8, srcA + kk);
    gld16(s + 4096 + tid * 8, srcB0 + kk);
    gld16(s + 8192 + tid * 8, srcB1 + kk);
  };

  // ---- GEMM1: S[64 tok][128 e], K=1024, BK=64, 2-phase dbuf
  f32x4 acc[2][2] = {};
  stg1(0, 0);
  __syncthreads();
  for (int t = 0; t < 16; ++t) {
    int curB = (t & 1) * 24576;
    if (t < 15) stg1(((t + 1) & 1) * 24576, (t + 1) * 64);
    bf16x8 aF[2][2], bF[2][2];
#pragma unroll
    for (int ks = 0; ks < 2; ++ks) {
#pragma unroll
      for (int m = 0; m < 2; ++m) {
        int r = wr * 32 + m * 16 + cc;
        aF[ks][m] = *reinterpret_cast<const bf16x8*>(
            sbase + curB + r * 128 + (((ks * 4 + grp) ^ (r & 7)) * 16));
      }
#pragma unroll
      for (int n = 0; n < 2; ++n) {
        int r = wc * 32 + n * 16 + cc;
        bF[ks][n] = *reinterpret_cast<const bf16x8*>(
            sbase + curB + 8192 + r * 128 + (((ks * 4 + grp) ^ (r & 7)) * 16));
      }
    }
#pragma unroll
    for (int ks = 0; ks < 2; ++ks)
#pragma unroll
      for (int m = 0; m < 2; ++m)
#pragma unroll
        for (int n = 0; n < 2; ++n)
          acc[m][n] = __builtin_amdgcn_mfma_f32_16x16x32_bf16(aF[ks][m], bF[ks][n], acc[m][n], 0, 0, 0);
    __syncthreads();
  }
  // After this barrier ALL reads of the GEMM1 dbuf are retired -> regions reusable.

  // ---- V staging bases (256B rows -> 16 chunks, swz mask row&15)
  int v0row = tid >> 4, vch = tid & 15;
  int v1row = 32 + v0row;
  const unsigned short* srcV0 = vb + (size_t)v0row * ESIZE + ((vch ^ (v0row & 15)) * 8);
  const unsigned short* srcV1 = vb + (size_t)v1row * ESIZE + ((vch ^ (v1row & 15)) * 8);
  auto stgV = [&](int boB, int ch) {
    unsigned short* s = (unsigned short*)(sbase + boB);
    const size_t co = (size_t)ch * 64 * ESIZE;
    gld16(s + tid * 8, srcV0 + co);
    gld16(s + 4096 + tid * 8, srcV1 + co);
  };

  stgV(17408, 0);  // overlap chunk-0 V load with the relu/lS phase

  // relu*gate -> lS overlay at stage bytes [0, 17408), stride 136 ushorts
#pragma unroll
  for (int m = 0; m < 2; ++m) {
    int trow = wr * 32 + m * 16 + grp * 4;
#pragma unroll
    for (int n = 0; n < 2; ++n) {
      int e = wc * 32 + n * 16 + cc;
#pragma unroll
      for (int r = 0; r < 4; ++r) {
        float s = acc[m][n][r];
        s = s > 0.0f ? s * sGate[trow + r] : 0.0f;
        stage[(trow + r) * 136 + e] = f2bf(s);
      }
    }
  }
  __syncthreads();  // lS visible + V chunk0 staged

  // S-frags (held in registers across all chunks)
  bf16x8 sF[2][4];
#pragma unroll
  for (int m = 0; m < 2; ++m) {
    int r = wr * 32 + m * 16 + cc;
#pragma unroll
    for (int ks = 0; ks < 4; ++ks)
      sF[m][ks] = *reinterpret_cast<const bf16x8*>((const char*)stage + r * 272 + ks * 64 + grp * 16);
  }
  unsigned short* rB[2][4];
#pragma unroll
  for (int m = 0; m < 2; ++m)
#pragma unroll
    for (int r = 0; r < 4; ++r)
      rB[m][r] = part + (size_t)sRow[wr * 32 + m * 16 + grp * 4 + r] * DMODEL + wc * 16 + cc;

  // ---- GEMM2: out[64 tok][1024 v], 16 chunks of 64 v-cols, 2-phase dbuf
  for (int ch = 0; ch < 16; ++ch) {
    int curB = 17408 + (ch & 1) * 16384;
    if (ch < 15) stgV(17408 + (((ch + 1) & 1) * 16384), ch + 1);
    int r = wc * 16 + cc;
    bf16x8 vF[4];
#pragma unroll
    for (int ks = 0; ks < 4; ++ks)
      vF[ks] = *reinterpret_cast<const bf16x8*>(
          sbase + curB + r * 256 + (((ks * 4 + grp) ^ cc) * 16));
    f32x4 o[2] = {};
#pragma unroll
    for (int ks = 0; ks < 4; ++ks)
#pragma unroll
      for (int m = 0; m < 2; ++m)
        o[m] = __builtin_amdgcn_mfma_f32_16x16x32_bf16(sF[m][ks], vF[ks], o[m], 0, 0, 0);
#pragma unroll
    for (int m = 0; m < 2; ++m)
#pragma unroll
      for (int r2 = 0; r2 < 4; ++r2)
        rB[m][r2][ch * 64] = f2bf(o[m][r2]);
    __syncthreads();
  }
}

// K7: out[n][v] = sum_h part[h*N_TOK+n][v]  (bf16 partials -> fp32 out, full overwrite)
__global__ void k_sum(const unsigned short* __restrict__ part, float* __restrict__ out) {
  size_t i = ((size_t)blockIdx.x * 256 + threadIdx.x) * 8;
  const size_t stride = (size_t)N_TOK * DMODEL;
  uint4 a = *reinterpret_cast<const uint4*>(part + i);
  uint4 b = *reinterpret_cast<const uint4*>(part + stride + i);
  uint4 c = *reinterpret_cast<const uint4*>(part + 2 * stride + i);
  uint4 d = *reinterpret_cast<const uint4*>(part + 3 * stride + i);
  float o[8];
#pragma unroll
  for (int q = 0; q < 4; ++q) {
    unsigned ua = (&a.x)[q], ub = (&b.x)[q], uc = (&c.x)[q], ud = (&d.x)[q];
    o[q * 2 + 0] = b2f((unsigned short)ua) + b2f((unsigned short)ub) +
                   b2f((unsigned short)uc) + b2f((unsigned short)ud);
    o[q * 2 + 1] = b2f((unsigned short)(ua >> 16)) + b2f((unsigned short)(ub >> 16)) +
                   b2f((unsigned short)(uc >> 16)) + b2f((unsigned short)(ud >> 16));
  }
  *reinterpret_cast<float4*>(out + i) = make_float4(o[0], o[1], o[2], o[3]);
  *reinterpret_cast<float4*>(out + i + 4) = make_float4(o[4], o[5], o[6], o[7]);
}

extern "C" void kernel_launch(void* const* d_in, const int* in_sizes, int n_in,
                              void* d_out, int out_size, void* d_ws, size_t ws_size,
                              hipStream_t stream) {
  const float* x = (const float*)d_in[0];
  const float* esel = (const float*)d_in[1];
  const float* keys = (const float*)d_in[2];
  const float* values = (const float*)d_in[3];
  float* out = (float*)d_out;

  char* p = (char*)d_ws;
  unsigned short* xbf = (unsigned short*)p; p += (size_t)N_TOK * DMODEL * 2;
  unsigned short* xlo = (unsigned short*)p; p += (size_t)N_TOK * DMODEL * 2;
  unsigned short* kbf = (unsigned short*)p; p += (size_t)NEXP * DMODEL * ESIZE * 2;
  unsigned short* vbf = (unsigned short*)p; p += (size_t)NEXP * DMODEL * ESIZE * 2;
  unsigned short* selbh = (unsigned short*)p; p += (size_t)NEXP * DMODEL * 2;
  unsigned short* selbl = (unsigned short*)p; p += (size_t)NEXP * DMODEL * 2;
  float4* g4 = (float4*)p; p += (size_t)N_TOK * 16;
  int4* idx4 = (int4*)p; p += (size_t)N_TOK * 16;
  int* btok = (int*)p; p += (size_t)NEXP * N_TOK * 4;
  float* bgate = (float*)p; p += (size_t)NEXP * N_TOK * 4;
  unsigned short* part = (unsigned short*)p;
  p += ((size_t)4 * N_TOK + WL_MAX) * DMODEL * 2;  // + per-block dump rows
  int* cnt = (int*)p; p += 512;      // cnt + pad, zeroed by k_prep (128 ints)
  int* flags = (int*)p; p += N_TOK * 4;
  (void)ws_size; (void)in_sizes; (void)n_in;

  k_prep<<<PREP_SPLIT, 256, 0, stream>>>(x, xbf, xlo, esel, selbh, selbl, cnt);
  k_rlogit<<<256 + 2048, 512, 0, stream>>>(xbf, xlo, selbh, selbl, keys, kbf,
                                           values, vbf, idx4, g4, flags);
  k_bucket<<<32, 256, 0, stream>>>(idx4, g4, x, esel, flags, btok, bgate, cnt);
  k_expert<<<WL_MAX, 512, 0, stream>>>(xbf, kbf, vbf, btok, bgate, cnt, part);
  k_sum<<<(N_TOK * DMODEL / 8) / 256, 256, 0, stream>>>(part, out);
}

// Round 23
// 129.886 us; speedup vs baseline: 1.0842x; 1.0842x over previous
//
#include <hip/hip_runtime.h>

typedef __bf16 bf16x8 __attribute__((ext_vector_type(8)));
typedef float f32x4 __attribute__((ext_vector_type(4)));

#define N_TOK 8192
#define DMODEL 1024
#define NEXP 64
#define ESIZE 128
#define WL_MAX 576    // sum ceil(ck/64) <= 32768/64 + 64 = 576 (divisible by 8)
#define PREP_SPLIT 2064  // 2048 blocks for x + 16 for esel (16 elems/thread)

__device__ __forceinline__ unsigned short f2bf(float f) {
  unsigned int u = __builtin_bit_cast(unsigned int, f);
  u += 0x7FFFu + ((u >> 16) & 1u);
  return (unsigned short)(u >> 16);
}

__device__ __forceinline__ float b2f(unsigned short u) {
  unsigned int v = ((unsigned int)u) << 16;
  return __builtin_bit_cast(float, v);
}

// async global->LDS, 16B per lane. LDS dest lane-linear within the wave.
__device__ __forceinline__ void gld16(unsigned short* lds, const unsigned short* g) {
  __builtin_amdgcn_global_load_lds(
      (const __attribute__((address_space(1))) unsigned int*)g,
      (__attribute__((address_space(3))) unsigned int*)lds, 16, 0, 0);
}

// K1: split-only prep — fp32->bf16 hi/lo split of x and expert_sel
// (16 elems/thread) + zero cnt/gcount. Transpose lives in k_rlogit's grid.
__global__ void k_prep(const float* __restrict__ x, unsigned short* __restrict__ xh,
                       unsigned short* __restrict__ xl, const float* __restrict__ esel,
                       unsigned short* __restrict__ sh_, unsigned short* __restrict__ sl_,
                       int* __restrict__ zeroPtr) {
  int bid = blockIdx.x, tid = threadIdx.x;
  if (bid == 0 && tid < 128) zeroPtr[tid] = 0;
  size_t gid = (size_t)bid * 256 + tid;
  const size_t NX = (size_t)N_TOK * DMODEL / 16;
  const float* in;
  unsigned short *ho, *lo2;
  size_t i;
  if (gid < NX) {
    in = x; ho = xh; lo2 = xl; i = gid * 16;
  } else {
    in = esel; ho = sh_; lo2 = sl_; i = (gid - NX) * 16;
  }
#pragma unroll
  for (int c = 0; c < 2; ++c) {
    size_t ii = i + c * 8;
    float4 a = *reinterpret_cast<const float4*>(in + ii);
    float4 b = *reinterpret_cast<const float4*>(in + ii + 4);
    unsigned short h[8], l[8];
    float v[8] = {a.x, a.y, a.z, a.w, b.x, b.y, b.z, b.w};
#pragma unroll
    for (int q = 0; q < 8; ++q) {
      h[q] = f2bf(v[q]);
      l[q] = f2bf(v[q] - b2f(h[q]));
    }
    uint4 oh, ol;
    oh.x = h[0] | ((unsigned)h[1] << 16); oh.y = h[2] | ((unsigned)h[3] << 16);
    oh.z = h[4] | ((unsigned)h[5] << 16); oh.w = h[6] | ((unsigned)h[7] << 16);
    ol.x = l[0] | ((unsigned)l[1] << 16); ol.y = l[2] | ((unsigned)l[3] << 16);
    ol.z = l[4] | ((unsigned)l[5] << 16); ol.w = l[6] | ((unsigned)l[7] << 16);
    *reinterpret_cast<uint4*>(ho + ii) = oh;
    *reinterpret_cast<uint4*>(lo2 + ii) = ol;
  }
}

// K3: router + overlapped keys/values transpose.
// Blocks [0,256): bf16x3 split-precision MFMA logit GEMM, 512 threads / 8 waves.
// Blocks [256, 256+2048): 64x64 transpose+cast tiles (2 per block).
// LDS = stage only (48KB); logits OVERLAY stage after the GEMM loop (stage dead)
// -> 3 blocks/CU for both paths.
__global__ __launch_bounds__(512) void k_rlogit(const unsigned short* __restrict__ xh,
                                                const unsigned short* __restrict__ xl,
                                                const unsigned short* __restrict__ sh,
                                                const unsigned short* __restrict__ sl,
                                                const float* __restrict__ keys,
                                                unsigned short* __restrict__ kout,
                                                const float* __restrict__ values,
                                                unsigned short* __restrict__ vout,
                                                int4* __restrict__ idx4,
                                                float4* __restrict__ g4,
                                                int* __restrict__ gcount,
                                                int* __restrict__ glist) {
  int tid = threadIdx.x, lane = tid & 63;

  __shared__ alignas(16) unsigned short stage[24576];  // 48KB (union: dbuf / tiles / logits)

  if (blockIdx.x >= 256) {
    // ---- transpose path: 2 independent 64x64 tiles per block
    int tt = (blockIdx.x - 256) * 2 + (tid >> 8);  // 0..4095
    int ts = tid & 255;
    float* tb = (float*)stage + (tid >> 8) * (64 * 65);  // 2 x 16.6KB <= 48KB
    const float* in;
    unsigned short* out;
    int R, C;
    if (tt < 2048) { in = keys; out = kout; R = DMODEL; C = ESIZE; }
    else { in = values; out = vout; R = ESIZE; C = DMODEL; tt -= 2048; }
    int b = tt >> 5, tile = tt & 31;
    int tilesC = C >> 6;
    int tr = tile / tilesC, tc = tile % tilesC;
    const float* ip = in + (size_t)b * R * C + (size_t)tr * 64 * C + tc * 64;
    unsigned short* op = out + (size_t)b * R * C + (size_t)tc * 64 * R + tr * 64;

    int lr = ts >> 4, lc4 = (ts & 15) * 4;
#pragma unroll
    for (int p = 0; p < 4; ++p) {
      int row = p * 16 + lr;
      *reinterpret_cast<float4*>(&tb[row * 65 + lc4]) =
          *reinterpret_cast<const float4*>(ip + (size_t)row * C + lc4);
    }
    __syncthreads();
    int orow = ts >> 3, oc = (ts & 7) * 8;
#pragma unroll
    for (int p = 0; p < 2; ++p) {
      int row = p * 32 + orow;
      unsigned short h[8];
#pragma unroll
      for (int j = 0; j < 8; ++j) h[j] = f2bf(tb[(oc + j) * 65 + row]);
      uint4 ov;
      ov.x = h[0] | ((unsigned)h[1] << 16); ov.y = h[2] | ((unsigned)h[3] << 16);
      ov.z = h[4] | ((unsigned)h[5] << 16); ov.w = h[6] | ((unsigned)h[7] << 16);
      *reinterpret_cast<uint4*>(op + (size_t)row * R + oc) = ov;
    }
    return;
  }

  // ---- routing path (r19-validated structure)
  int tok0 = blockIdx.x * 32;
  int wv = tid >> 6, wr = wv >> 2, wc = wv & 3;
  int cc = lane & 15, grp = lane >> 4;

  int aslot = tid & 255;
  int arow = aslot >> 3, ach = aslot & 7;
  const unsigned short* srcA = (tid < 256 ? xh : xl) +
      (size_t)(tok0 + arow) * DMODEL + ((ach ^ (arow & 7)) * 8);
  int brow = tid >> 3, bch = tid & 7;  // 64 rows x 8 chunks
  int bsw = (bch ^ (brow & 7)) * 8;
  const unsigned short* srcBh = sh + (size_t)brow * DMODEL + bsw;
  const unsigned short* srcBl = sl + (size_t)brow * DMODEL + bsw;

  auto stg = [&](int bo /*ushort offset*/, int kk) {
    unsigned short* s = stage + bo;
    gld16(s + tid * 8, srcA + kk);          // Ah ushorts [0,2048) | Al [2048,4096)
    gld16(s + 4096 + tid * 8, srcBh + kk);  // Bh ushorts [4096,8192)
    gld16(s + 8192 + tid * 8, srcBl + kk);  // Bl ushorts [8192,12288)
  };

  f32x4 acc = {};
  stg(0, 0);
  __syncthreads();
  const char* sb = (const char*)stage;
  int ra = wr * 16 + cc;
  int rb = wc * 16 + cc;
  for (int t = 0; t < 16; ++t) {
    int curB = (t & 1) * 24576;  // bytes
    if (t < 15) stg(((t + 1) & 1) * 12288, (t + 1) * 64);
#pragma unroll
    for (int ks = 0; ks < 2; ++ks) {
      int o_a = (((ks * 4 + grp) ^ (ra & 7)) * 16);
      int o_b = (((ks * 4 + grp) ^ (rb & 7)) * 16);
      bf16x8 aH = *reinterpret_cast<const bf16x8*>(sb + curB + ra * 128 + o_a);
      bf16x8 aL = *reinterpret_cast<const bf16x8*>(sb + curB + 4096 + ra * 128 + o_a);
      bf16x8 bH = *reinterpret_cast<const bf16x8*>(sb + curB + 8192 + rb * 128 + o_b);
      bf16x8 bL = *reinterpret_cast<const bf16x8*>(sb + curB + 16384 + rb * 128 + o_b);
      acc = __builtin_amdgcn_mfma_f32_16x16x32_bf16(aH, bH, acc, 0, 0, 0);
      acc = __builtin_amdgcn_mfma_f32_16x16x32_bf16(aH, bL, acc, 0, 0, 0);
      acc = __builtin_amdgcn_mfma_f32_16x16x32_bf16(aL, bH, acc, 0, 0, 0);
    }
    __syncthreads();
  }
  // Final barrier retired ALL stage reads -> overlay logits at stage bytes [0,8704).

  float* lg = (float*)stage;  // [32][68] overlay
  // C layout (verified): col(expert) = lane&15, row(token) = grp*4 + r
#pragma unroll
  for (int r = 0; r < 4; ++r)
    lg[(wr * 16 + grp * 4 + r) * 68 + wc * 16 + cc] = acc[r];
  __syncthreads();

  if (tid < 32) {
    float bv0 = -3e38f, bv1 = -3e38f, bv2 = -3e38f, bv3 = -3e38f, bv4 = -3e38f;
    int bi0 = 0, bi1 = 0, bi2 = 0, bi3 = 0;
    for (int e = 0; e < 64; ++e) {
      float v = lg[tid * 68 + e];
      if (v > bv4) {
        if (v > bv0) {
          bv4 = bv3; bv3 = bv2; bi3 = bi2; bv2 = bv1; bi2 = bi1; bv1 = bv0; bi1 = bi0; bv0 = v; bi0 = e;
        } else if (v > bv1) {
          bv4 = bv3; bv3 = bv2; bi3 = bi2; bv2 = bv1; bi2 = bi1; bv1 = v; bi1 = e;
        } else if (v > bv2) {
          bv4 = bv3; bv3 = bv2; bi3 = bi2; bv2 = v; bi2 = e;
        } else if (v > bv3) {
          bv4 = bv3; bv3 = v; bi3 = e;
        } else {
          bv4 = v;
        }
      }
    }
    idx4[tok0 + tid] = make_int4(bi0, bi1, bi2, bi3);
    float4 g;
    g.x = 1.0f / (1.0f + __expf(-bv0));
    g.y = 1.0f / (1.0f + __expf(-bv1));
    g.z = 1.0f / (1.0f + __expf(-bv2));
    g.w = 1.0f / (1.0f + __expf(-bv3));
    g4[tok0 + tid] = g;
    if (bv3 - bv4 < 1e-4f) {
      int p = atomicAdd(gcount, 1);
      glist[p] = tok0 + tid;
    }
  }
}

// K3b: exact fp64 re-ranking of flagged near-tie tokens (expected ~10 tokens).
__global__ __launch_bounds__(256) void k_refine(const float* __restrict__ x,
                                                const float* __restrict__ esel,
                                                const int* __restrict__ gcount,
                                                const int* __restrict__ glist,
                                                int4* __restrict__ idx4,
                                                float4* __restrict__ g4) {
  __shared__ double lp[256];
  __shared__ double lgt[64];
  int cnt = *gcount;
  for (int i = blockIdx.x; i < cnt; i += 64) {
    int n = glist[i];
    int e = threadIdx.x & 63, jq = threadIdx.x >> 6;
    const float* xr = x + (size_t)n * DMODEL + jq * 256;
    const float* er = esel + (size_t)e * DMODEL + jq * 256;
    double s = 0.0;
    for (int j = 0; j < 256; ++j)
      s += (double)xr[j] * (double)er[j];
    lp[threadIdx.x] = s;
    __syncthreads();
    if (threadIdx.x < 64)
      lgt[threadIdx.x] =
          lp[threadIdx.x] + lp[64 + threadIdx.x] + lp[128 + threadIdx.x] + lp[192 + threadIdx.x];
    __syncthreads();
    if (threadIdx.x == 0) {
      double bv0 = -1.0e300, bv1 = -1.0e300, bv2 = -1.0e300, bv3 = -1.0e300;
      int bi0 = 0, bi1 = 0, bi2 = 0, bi3 = 0;
      for (int e2 = 0; e2 < 64; ++e2) {
        double v = lgt[e2];
        if (v > bv3) {
          if (v > bv0) {
            bv3 = bv2; bi3 = bi2; bv2 = bv1; bi2 = bi1; bv1 = bv0; bi1 = bi0; bv0 = v; bi0 = e2;
          } else if (v > bv1) {
            bv3 = bv2; bi3 = bi2; bv2 = bv1; bi2 = bi1; bv1 = v; bi1 = e2;
          } else if (v > bv2) {
            bv3 = bv2; bi3 = bi2; bv2 = v; bi2 = e2;
          } else {
            bv3 = v; bi3 = e2;
          }
        }
      }
      idx4[n] = make_int4(bi0, bi1, bi2, bi3);
      float4 g;
      g.x = 1.0f / (1.0f + __expf(-(float)bv0));
      g.y = 1.0f / (1.0f + __expf(-(float)bv1));
      g.z = 1.0f / (1.0f + __expf(-(float)bv2));
      g.w = 1.0f / (1.0f + __expf(-(float)bv3));
      g4[n] = g;
    }
    __syncthreads();
  }
}

// K4: two-level atomic bucketize (slot order non-deterministic; output invariant).
__global__ __launch_bounds__(256) void k_bucket(const int4* __restrict__ idx4,
                                                const float4* __restrict__ g4,
                                                int* __restrict__ btok,
                                                float* __restrict__ bgate,
                                                int* __restrict__ cnt) {
  __shared__ int lcnt[64];
  __shared__ int lbase[64];
  int tid = threadIdx.x;
  if (tid < 64) lcnt[tid] = 0;
  __syncthreads();
  int n = blockIdx.x * 256 + tid;
  int4 I = idx4[n];
  float4 G = g4[n];
  int e[4] = {I.x, I.y, I.z, I.w};
  float g[4] = {G.x, G.y, G.z, G.w};
  int pos[4];
#pragma unroll
  for (int h = 0; h < 4; ++h) pos[h] = atomicAdd(&lcnt[e[h]], 1);
  __syncthreads();
  if (tid < 64 && lcnt[tid] > 0) lbase[tid] = atomicAdd(&cnt[tid], lcnt[tid]);
  __syncthreads();
#pragma unroll
  for (int h = 0; h < 4; ++h) {
    int slot = lbase[e[h]] + pos[h];
    btok[e[h] * N_TOK + slot] = h * N_TOK + n;
    bgate[e[h] * N_TOK + slot] = g[h];
  }
}

// K5: compact worklist of (expert, tile64) pairs. 1 block, 64 threads.
__global__ void k_worklist(const int* __restrict__ cnt, int* __restrict__ wl) {
  int lane = threadIdx.x;
  int nt = (cnt[lane] + 63) >> 6;
  int off = nt;
  for (int d = 1; d < 64; d <<= 1) {
    int o = __shfl_up(off, d);
    if (lane >= d) off += o;
  }
  int total = __shfl(off, 63);
  off -= nt;
  for (int t = 0; t < nt; ++t) wl[off + t] = (lane << 8) | t;
  for (int i = total + lane; i < WL_MAX; i += 64) wl[i] = -1;
}

// K6: fused per-(expert,tile64), r11 barrier structure, LDS OVERLAY:
// GEMM1 dbuf bytes [0,49152); lS overlay [0,17408); V dbuf [17408,50176).
// Total LDS ~50.7KB -> 3 blocks/CU (24 waves/CU) for cross-block stall hiding.
__global__ __launch_bounds__(512, 6) void k_expert(
    const unsigned short* __restrict__ xbf, const unsigned short* __restrict__ kbf,
    const unsigned short* __restrict__ vbf, const int* __restrict__ wl,
    const int* __restrict__ btok, const float* __restrict__ bgate,
    const int* __restrict__ cnt, unsigned short* __restrict__ part) {
  int wid = (blockIdx.x & 7) * (WL_MAX / 8) + (blockIdx.x >> 3);
  int wle = wl[wid];
  if (wle < 0) return;
  int k = wle >> 8, tile = wle & 255;
  int ck = cnt[k];
  int tid = threadIdx.x, lane = tid & 63;
  int wv = tid >> 6, wr = wv >> 2, wc = wv & 3;
  int cc = lane & 15, grp = lane >> 4;

  __shared__ alignas(16) unsigned short stage[25088];  // 50176 B, multi-purpose
  __shared__ int sRow[64];
  __shared__ float sGate[64];

  if (tid < 64) {
    int i = tile * 64 + tid;
    bool valid = i < ck;
    sRow[tid] = valid ? btok[k * N_TOK + i] : 4 * N_TOK + wid;  // per-block dump row
    sGate[tid] = valid ? bgate[k * N_TOK + i] : 0.0f;
  }
  __syncthreads();

  const unsigned short* kb = kbf + (size_t)k * (ESIZE * DMODEL);
  const unsigned short* vb = vbf + (size_t)k * (DMODEL * ESIZE);
  char* sbase = (char*)stage;

  // ---- GEMM1 staging bases (src chunk = phys ^ (row&7), LDS dest lane-linear)
  int arow = tid >> 3, ach = tid & 7;
  const unsigned short* srcA =
      xbf + (size_t)(sRow[arow] & (N_TOK - 1)) * DMODEL + ((ach ^ (arow & 7)) * 8);
  int b1row = 64 + arow;
  const unsigned short* srcB0 = kb + (size_t)arow * DMODEL + ((ach ^ (arow & 7)) * 8);
  const unsigned short* srcB1 = kb + (size_t)b1row * DMODEL + ((ach ^ (b1row & 7)) * 8);

  auto stg1 = [&](int boB, int kk) {
    unsigned short* s = (unsigned short*)(sbase + boB);
    gld16(s + tid * 8, srcA + kk);
    gld16(s + 4096 + tid * 8, srcB0 + kk);
    gld16(s + 8192 + tid * 8, srcB1 + kk);
  };

  // ---- GEMM1: S[64 tok][128 e], K=1024, BK=64, 2-phase dbuf
  f32x4 acc[2][2] = {};
  stg1(0, 0);
  __syncthreads();
  for (int t = 0; t < 16; ++t) {
    int curB = (t & 1) * 24576;
    if (t < 15) stg1(((t + 1) & 1) * 24576, (t + 1) * 64);
    bf16x8 aF[2][2], bF[2][2];
#pragma unroll
    for (int ks = 0; ks < 2; ++ks) {
#pragma unroll
      for (int m = 0; m < 2; ++m) {
        int r = wr * 32 + m * 16 + cc;
        aF[ks][m] = *reinterpret_cast<const bf16x8*>(
            sbase + curB + r * 128 + (((ks * 4 + grp) ^ (r & 7)) * 16));
      }
#pragma unroll
      for (int n = 0; n < 2; ++n) {
        int r = wc * 32 + n * 16 + cc;
        bF[ks][n] = *reinterpret_cast<const bf16x8*>(
            sbase + curB + 8192 + r * 128 + (((ks * 4 + grp) ^ (r & 7)) * 16));
      }
    }
#pragma unroll
    for (int ks = 0; ks < 2; ++ks)
#pragma unroll
      for (int m = 0; m < 2; ++m)
#pragma unroll
        for (int n = 0; n < 2; ++n)
          acc[m][n] = __builtin_amdgcn_mfma_f32_16x16x32_bf16(aF[ks][m], bF[ks][n], acc[m][n], 0, 0, 0);
    __syncthreads();
  }
  // After this barrier ALL reads of the GEMM1 dbuf are retired -> regions reusable.

  // ---- V staging bases (256B rows -> 16 chunks, swz mask row&15)
  int v0row = tid >> 4, vch = tid & 15;
  int v1row = 32 + v0row;
  const unsigned short* srcV0 = vb + (size_t)v0row * ESIZE + ((vch ^ (v0row & 15)) * 8);
  const unsigned short* srcV1 = vb + (size_t)v1row * ESIZE + ((vch ^ (v1row & 15)) * 8);
  auto stgV = [&](int boB, int ch) {
    unsigned short* s = (unsigned short*)(sbase + boB);
    const size_t co = (size_t)ch * 64 * ESIZE;
    gld16(s + tid * 8, srcV0 + co);
    gld16(s + 4096 + tid * 8, srcV1 + co);
  };

  stgV(17408, 0);  // overlap chunk-0 V load with the relu/lS phase

  // relu*gate -> lS overlay at stage bytes [0, 17408), stride 136 ushorts
#pragma unroll
  for (int m = 0; m < 2; ++m) {
    int trow = wr * 32 + m * 16 + grp * 4;
#pragma unroll
    for (int n = 0; n < 2; ++n) {
      int e = wc * 32 + n * 16 + cc;
#pragma unroll
      for (int r = 0; r < 4; ++r) {
        float s = acc[m][n][r];
        s = s > 0.0f ? s * sGate[trow + r] : 0.0f;
        stage[(trow + r) * 136 + e] = f2bf(s);
      }
    }
  }
  __syncthreads();  // lS visible + V chunk0 staged

  // S-frags (held in registers across all chunks)
  bf16x8 sF[2][4];
#pragma unroll
  for (int m = 0; m < 2; ++m) {
    int r = wr * 32 + m * 16 + cc;
#pragma unroll
    for (int ks = 0; ks < 4; ++ks)
      sF[m][ks] = *reinterpret_cast<const bf16x8*>((const char*)stage + r * 272 + ks * 64 + grp * 16);
  }
  unsigned short* rB[2][4];
#pragma unroll
  for (int m = 0; m < 2; ++m)
#pragma unroll
    for (int r = 0; r < 4; ++r)
      rB[m][r] = part + (size_t)sRow[wr * 32 + m * 16 + grp * 4 + r] * DMODEL + wc * 16 + cc;

  // ---- GEMM2: out[64 tok][1024 v], 16 chunks of 64 v-cols, 2-phase dbuf
  for (int ch = 0; ch < 16; ++ch) {
    int curB = 17408 + (ch & 1) * 16384;
    if (ch < 15) stgV(17408 + (((ch + 1) & 1) * 16384), ch + 1);
    int r = wc * 16 + cc;
    bf16x8 vF[4];
#pragma unroll
    for (int ks = 0; ks < 4; ++ks)
      vF[ks] = *reinterpret_cast<const bf16x8*>(
          sbase + curB + r * 256 + (((ks * 4 + grp) ^ cc) * 16));
    f32x4 o[2] = {};
#pragma unroll
    for (int ks = 0; ks < 4; ++ks)
#pragma unroll
      for (int m = 0; m < 2; ++m)
        o[m] = __builtin_amdgcn_mfma_f32_16x16x32_bf16(sF[m][ks], vF[ks], o[m], 0, 0, 0);
#pragma unroll
    for (int m = 0; m < 2; ++m)
#pragma unroll
      for (int r2 = 0; r2 < 4; ++r2)
        rB[m][r2][ch * 64] = f2bf(o[m][r2]);
    __syncthreads();
  }
}

// K7: out[n][v] = sum_h part[h*N_TOK+n][v]  (bf16 partials -> fp32 out, full overwrite)
__global__ void k_sum(const unsigned short* __restrict__ part, float* __restrict__ out) {
  size_t i = ((size_t)blockIdx.x * 256 + threadIdx.x) * 8;
  const size_t stride = (size_t)N_TOK * DMODEL;
  uint4 a = *reinterpret_cast<const uint4*>(part + i);
  uint4 b = *reinterpret_cast<const uint4*>(part + stride + i);
  uint4 c = *reinterpret_cast<const uint4*>(part + 2 * stride + i);
  uint4 d = *reinterpret_cast<const uint4*>(part + 3 * stride + i);
  float o[8];
#pragma unroll
  for (int q = 0; q < 4; ++q) {
    unsigned ua = (&a.x)[q], ub = (&b.x)[q], uc = (&c.x)[q], ud = (&d.x)[q];
    o[q * 2 + 0] = b2f((unsigned short)ua) + b2f((unsigned short)ub) +
                   b2f((unsigned short)uc) + b2f((unsigned short)ud);
    o[q * 2 + 1] = b2f((unsigned short)(ua >> 16)) + b2f((unsigned short)(ub >> 16)) +
                   b2f((unsigned short)(uc >> 16)) + b2f((unsigned short)(ud >> 16));
  }
  *reinterpret_cast<float4*>(out + i) = make_float4(o[0], o[1], o[2], o[3]);
  *reinterpret_cast<float4*>(out + i + 4) = make_float4(o[4], o[5], o[6], o[7]);
}

extern "C" void kernel_launch(void* const* d_in, const int* in_sizes, int n_in,
                              void* d_out, int out_size, void* d_ws, size_t ws_size,
                              hipStream_t stream) {
  const float* x = (const float*)d_in[0];
  const float* esel = (const float*)d_in[1];
  const float* keys = (const float*)d_in[2];
  const float* values = (const float*)d_in[3];
  float* out = (float*)d_out;

  char* p = (char*)d_ws;
  unsigned short* xbf = (unsigned short*)p; p += (size_t)N_TOK * DMODEL * 2;
  unsigned short* xlo = (unsigned short*)p; p += (size_t)N_TOK * DMODEL * 2;
  unsigned short* kbf = (unsigned short*)p; p += (size_t)NEXP * DMODEL * ESIZE * 2;
  unsigned short* vbf = (unsigned short*)p; p += (size_t)NEXP * DMODEL * ESIZE * 2;
  unsigned short* selbh = (unsigned short*)p; p += (size_t)NEXP * DMODEL * 2;
  unsigned short* selbl = (unsigned short*)p; p += (size_t)NEXP * DMODEL * 2;
  float4* g4 = (float4*)p; p += (size_t)N_TOK * 16;
  int4* idx4 = (int4*)p; p += (size_t)N_TOK * 16;
  int* btok = (int*)p; p += (size_t)NEXP * N_TOK * 4;
  float* bgate = (float*)p; p += (size_t)NEXP * N_TOK * 4;
  unsigned short* part = (unsigned short*)p;
  p += ((size_t)4 * N_TOK + WL_MAX) * DMODEL * 2;  // + per-block dump rows
  int* cnt = (int*)p; p += 256;      // zeroed by k_prep (cnt + gcount = 512B)
  int* gcount = (int*)p; p += 256;
  int* wl = (int*)p; p += WL_MAX * 4;
  int* glist = (int*)p; p += N_TOK * 4;
  (void)ws_size; (void)in_sizes; (void)n_in;

  k_prep<<<PREP_SPLIT, 256, 0, stream>>>(x, xbf, xlo, esel, selbh, selbl, cnt);
  k_rlogit<<<256 + 2048, 512, 0, stream>>>(xbf, xlo, selbh, selbl, keys, kbf,
                                           values, vbf, idx4, g4, gcount, glist);
  k_refine<<<64, 256, 0, stream>>>(x, esel, gcount, glist, idx4, g4);
  k_bucket<<<32, 256, 0, stream>>>(idx4, g4, btok, bgate, cnt);
  k_worklist<<<1, 64, 0, stream>>>(cnt, wl);
  k_expert<<<WL_MAX, 512, 0, stream>>>(xbf, kbf, vbf, wl, btok, bgate, cnt, part);
  k_sum<<<(N_TOK * DMODEL / 8) / 256, 256, 0, stream>>>(part, out);
}